// Round 17
// baseline (300.726 us; speedup 1.0000x reference)
//
#include <hip/hip_runtime.h>

typedef float f4 __attribute__((ext_vector_type(4)));
typedef __attribute__((ext_vector_type(4))) float f32x4;
typedef _Float16 h8 __attribute__((ext_vector_type(8)));
typedef _Float16 h4 __attribute__((ext_vector_type(4)));

__global__ __launch_bounds__(256, 3)
void avif_pipe7(const float* __restrict__ x, const float* __restrict__ twm,
                const float* __restrict__ w1, const float* __restrict__ b1,
                const float* __restrict__ w2, const float* __restrict__ b2,
                float* __restrict__ out)
{
    // xs: x tile in FP16. Channel c = 128 ushorts (256B); granule g2 = r*2+half
    // (16B = 8 px of row r) stored at slot s = g2 ^ (c&15).
    __shared__ ushort xs[64 * 128];   // 16 KB
    __shared__ ushort ysf[128][64];   // 16 KB (r8-verified swizzle)
    __shared__ ushort hsf[128][64];   // 16 KB  -> 48 KB => 3 blocks/CU

    const int t = threadIdx.x;
    const int bid = blockIdx.x;
    // pair-interleaved decode (r10-verified): bid and bid+256 share (b,hb),
    // differ in wc -> same XCD -> both 64B halves of each 128B x/out line
    // touched in the same tile iteration -> L2 merge.
    const int wc  = bid >> 8;
    const int rem = bid & 255;
    const int hb  = rem & 63;
    const int b   = rem >> 6;

    const int wv = t >> 6, lane = t & 63;
    const int li = lane & 15, lg = lane >> 4, l7 = li & 7;
    const int lb3 = (li >> 3) << 2;

    // ---- staging maps: unit vid = j*256+t -> (c = vid>>4, sub = vid&15),
    // r = sub>>1, half = sub&1. Global: 32B half-row (wave covers full 64B
    // lines, r10 pattern). LDS: h8 granule at slot sub^(c&15). ----
    const float* xslab = x + (((size_t)(b * 64)) * 512 + (size_t)hb * 8) * 512 + wc * 16;
    const float* gq[4];
    int ls[4];
#pragma unroll
    for (int j = 0; j < 4; ++j) {
        const int vid = j * 256 + t;
        const int cc = vid >> 4, sub = vid & 15;
        const int r = sub >> 1, half = sub & 1;
        gq[j] = xslab + (size_t)cc * 262144 + r * 512 + half * 8;
        ls[j] = cc * 128 + ((sub ^ (cc & 15)) << 3);
    }

    // ---- W fragments (fp16) + biases (r8/r10 verified) ----
    h8 w1f[2], w2f[2];
    {
        const float* p1 = w1 + (16 * wv + li) * 64 + lg * 8;
        const float* p2 = w2 + (16 * wv + li) * 64 + lg * 8;
#pragma unroll
        for (int kk = 0; kk < 2; ++kk) {
            f4 a = *(const f4*)(p1 + kk * 32);
            f4 d = *(const f4*)(p1 + kk * 32 + 4);
            h8 f;
#pragma unroll
            for (int q = 0; q < 4; ++q) { f[q] = (_Float16)a[q]; f[4 + q] = (_Float16)d[q]; }
            w1f[kk] = f;
            a = *(const f4*)(p2 + kk * 32);
            d = *(const f4*)(p2 + kk * 32 + 4);
#pragma unroll
            for (int q = 0; q < 4; ++q) { f[q] = (_Float16)a[q]; f[4 + q] = (_Float16)d[q]; }
            w2f[kk] = f;
        }
    }
    const int o0 = 16 * wv + 4 * lg;
    const f4 b1v = *(const f4*)(b1 + o0);
    const float b2s = b2[16 * wv + li];
    const int sg0 = ((lg       ^ l7 ^ lb3) << 3);
    const int sg1 = (((4 + lg) ^ l7 ^ lb3) << 3);
    const int go  = o0 >> 3, co = 4 * (lg & 1);
    const int ch  = 16 * wv + li;
    const int cgE = ch >> 3, c7E = li & 7;

    // ---- transform identity (lane pair shares (c,blk); q-partitioned) ----
    const int pid = t >> 1, h2 = t & 1;
    const int c   = pid & 63, blk = pid >> 6, Q0 = 4 * h2;
    const float* tB = twm + c * 64;
    const int xc = c * 128, c15 = c & 15;
    const int cg = c >> 3, c7 = c & 7;

    // ---- lean reg staging: 8 f4 in flight, issued at iteration top ----
    f4 Sa[4], Sd[4];
    auto stage_load = [&](int tile) {
#pragma unroll
        for (int j = 0; j < 4; ++j) {
            Sa[j] = *(const f4*)(gq[j] + tile * 32);
            Sd[j] = *(const f4*)(gq[j] + tile * 32 + 4);
        }
    };
    auto stage_write = [&]() {
#pragma unroll
        for (int j = 0; j < 4; ++j) {
            h8 hv;
#pragma unroll
            for (int e = 0; e < 4; ++e) {
                hv[e]     = (_Float16)Sa[j][e];
                hv[4 + e] = (_Float16)Sd[j][e];
            }
            *(h8*)&xs[ls[j]] = hv;
        }
    };

    // ================= prologue: stage tile 0 =================
    stage_load(0);
    stage_write();
    __syncthreads();

    for (int tile = 0; tile < 16; ++tile) {
        const int wt = 2 * tile + wc;
        if (tile < 15) stage_load(tile + 1);   // issue at top: full-iter cover

        // ---- transform: xs(h4 x2 passes) -> M -> Y -> ysf ----
        {
            float M[8][4];
            {
                f4 Ph[8];
#pragma unroll
                for (int i = 0; i < 8; ++i) {
                    h4 hv = *(const h4*)&xs[xc + (((i * 2 + blk) ^ c15) << 3)];
#pragma unroll
                    for (int e = 0; e < 4; ++e) Ph[i][e] = (float)hv[e];
                }
#pragma unroll
                for (int qq = 0; qq < 4; ++qq) {
                    f4 Th = *(const f4*)(tB + (Q0 + qq) * 8);
#pragma unroll
                    for (int i = 0; i < 8; ++i) {
                        float s = Ph[i][0] * Th[0];
                        s = fmaf(Ph[i][1], Th[1], s);
                        s = fmaf(Ph[i][2], Th[2], s);
                        s = fmaf(Ph[i][3], Th[3], s);
                        M[i][qq] = s;
                    }
                }
#pragma unroll
                for (int i = 0; i < 8; ++i) {
                    h4 hv = *(const h4*)&xs[xc + (((i * 2 + blk) ^ c15) << 3) + 4];
#pragma unroll
                    for (int e = 0; e < 4; ++e) Ph[i][e] = (float)hv[e];
                }
#pragma unroll
                for (int qq = 0; qq < 4; ++qq) {
                    f4 Th = *(const f4*)(tB + (Q0 + qq) * 8 + 4);
#pragma unroll
                    for (int i = 0; i < 8; ++i) {
                        float s = M[i][qq];
                        s = fmaf(Ph[i][0], Th[0], s);
                        s = fmaf(Ph[i][1], Th[1], s);
                        s = fmaf(Ph[i][2], Th[2], s);
                        s = fmaf(Ph[i][3], Th[3], s);
                        M[i][qq] = s;
                    }
                }
            }
#pragma unroll
            for (int p = 0; p < 8; ++p) {
                f4 a = *(const f4*)(tB + p * 8);
                f4 d = *(const f4*)(tB + p * 8 + 4);
                const int px0 = p * 16 + blk * 8;
#pragma unroll
                for (int qq = 0; qq < 4; ++qq) {
                    const int q = Q0 + qq;
                    float s = a[0] * M[0][qq];
                    s = fmaf(a[1], M[1][qq], s);
                    s = fmaf(a[2], M[2][qq], s);
                    s = fmaf(a[3], M[3][qq], s);
                    s = fmaf(d[0], M[4][qq], s);
                    s = fmaf(d[1], M[5][qq], s);
                    s = fmaf(d[2], M[6][qq], s);
                    s = fmaf(d[3], M[7][qq], s);
                    const int idx = ((cg ^ q ^ (blk << 2)) << 3) | c7;
                    *(_Float16*)&ysf[px0 + q][idx] = (_Float16)s;
                }
            }
        }
        __syncthreads();   // B1: ysf ready, xs consumed

        // ---- GEMM1: H = relu(W1 * Y + b1) ----
        f32x4 acc[8];
#pragma unroll
        for (int j = 0; j < 8; ++j) acc[j] = (f32x4){0.f, 0.f, 0.f, 0.f};
#pragma unroll
        for (int j = 0; j < 8; ++j) {
            const int row = 16 * j + li;
            h8 bh0 = *(const h8*)&ysf[row][sg0];
            h8 bh1 = *(const h8*)&ysf[row][sg1];
            acc[j] = __builtin_amdgcn_mfma_f32_16x16x32_f16(w1f[0], bh0, acc[j], 0, 0, 0);
            acc[j] = __builtin_amdgcn_mfma_f32_16x16x32_f16(w1f[1], bh1, acc[j], 0, 0, 0);
        }
#pragma unroll
        for (int j = 0; j < 8; ++j) {
            const int px = 16 * j + li;
            const int idx = ((go ^ l7 ^ lb3) << 3) + co;
            union { _Float16 h[2]; unsigned u; } p01, p23;
            p01.h[0] = (_Float16)fmaxf(acc[j][0] + b1v[0], 0.f);
            p01.h[1] = (_Float16)fmaxf(acc[j][1] + b1v[1], 0.f);
            p23.h[0] = (_Float16)fmaxf(acc[j][2] + b1v[2], 0.f);
            p23.h[1] = (_Float16)fmaxf(acc[j][3] + b1v[3], 0.f);
            *(unsigned*)&hsf[px][idx]     = p01.u;
            *(unsigned*)&hsf[px][idx + 2] = p23.u;
        }
        __syncthreads();   // B2: hsf ready

        // ---- GEMM2 swapped (A=H, B=W2): D[px][channel]; epilogue f4 stores ----
#pragma unroll
        for (int j = 0; j < 8; ++j) acc[j] = (f32x4){0.f, 0.f, 0.f, 0.f};
#pragma unroll
        for (int j = 0; j < 8; ++j) {
            const int row = 16 * j + li;
            h8 ah0 = *(const h8*)&hsf[row][sg0];
            h8 ah1 = *(const h8*)&hsf[row][sg1];
            acc[j] = __builtin_amdgcn_mfma_f32_16x16x32_f16(ah0, w2f[0], acc[j], 0, 0, 0);
            acc[j] = __builtin_amdgcn_mfma_f32_16x16x32_f16(ah1, w2f[1], acc[j], 0, 0, 0);
        }
        float* oB = out + ((size_t)(b * 64) + ch) * 262144
                    + (size_t)(hb * 8) * 512 + wt * 16 + 4 * lg;
#pragma unroll
        for (int j = 0; j < 8; ++j) {
            f4 r;
#pragma unroll
            for (int r4 = 0; r4 < 4; ++r4) {
                const int pc = 4 * lg + r4;
                const int px = 16 * j + pc;
                const int idx = ((cgE ^ (pc & 7) ^ (((pc >> 3) & 1) << 2)) << 3) | c7E;
                float yv = (float)(*(const _Float16*)&ysf[px][idx]);
                float z = acc[j][r4] + b2s;
                float g = __builtin_amdgcn_rcpf(1.f + __expf(-z));
                r[r4] = yv * g;
            }
            *(f4*)(oB + (size_t)j * 512) = r;
        }
        // cvt + write next tile's xs (xs dead since B1; all waves past B1)
        if (tile < 15) stage_write();
        __syncthreads();   // B3: xs(t+1) visible; ysf/hsf free
    }
}

extern "C" void kernel_launch(void* const* d_in, const int* in_sizes, int n_in,
                              void* d_out, int out_size, void* d_ws, size_t ws_size,
                              hipStream_t stream) {
    (void)in_sizes; (void)n_in; (void)out_size; (void)d_ws; (void)ws_size;
    const float* x   = (const float*)d_in[0];
    const float* twm = (const float*)d_in[1];
    const float* w1  = (const float*)d_in[2];
    const float* b1  = (const float*)d_in[3];
    const float* w2  = (const float*)d_in[4];
    const float* b2  = (const float*)d_in[5];
    float* out = (float*)d_out;

    avif_pipe7<<<dim3(512), dim3(256), 0, stream>>>(x, twm, w1, b1, w2, b2, out);
}

// Round 18
// 168.067 us; speedup vs baseline: 1.7893x; 1.7893x over previous
//
#include <hip/hip_runtime.h>

typedef float f4 __attribute__((ext_vector_type(4)));
typedef __attribute__((ext_vector_type(4))) float f32x4;
typedef _Float16 h8 __attribute__((ext_vector_type(8)));

__device__ __forceinline__ void gload_lds16(const float* g, float* l) {
    __builtin_amdgcn_global_load_lds(
        (const __attribute__((address_space(1))) void*)g,
        (__attribute__((address_space(3))) void*)l, 16, 0, 0);
}

__global__ __launch_bounds__(256, 2)
void avif_final(const float* __restrict__ x, const float* __restrict__ twm,
                const float* __restrict__ w1, const float* __restrict__ b1,
                const float* __restrict__ w2, const float* __restrict__ b2,
                float* __restrict__ out)
{
    // xs granule (16B) layout: (c, r, qg) -> G = c*32 + ((r*4+qg)^(c&7)),
    // staged linearly by G (global_load_lds dest must be linear); the XOR
    // lives in the per-lane GLOBAL source address.
    __shared__ float xs[8192];        // 32 KB
    __shared__ ushort ysf[128][64];   // Y fp16, swizzled (16 KB)
    __shared__ ushort hsf[128][64];   // H fp16, swizzled (16 KB)
    // ts: per-channel T matrices, fp32, granule-swizzled:
    // T[c][k] at float offset c*64 + ((kg ^ (c&15))<<2) + (k&3), kg=k>>2.
    __shared__ float ts[4096];        // 16 KB -> 80 KB total (2 blocks/CU)

    const int t = threadIdx.x;
    const int bid = blockIdx.x;
    // pair-interleaved decode: bid and bid+256 share (b,hb), differ in wc
    // -> same XCD -> both 64B halves of each 128B x/out line touched in the
    // same tile iteration -> L2 merge. Requires lockstep (full-drain) barriers.
    const int wc  = bid >> 8;
    const int rem = bid & 255;
    const int hb  = rem & 63;
    const int b   = rem >> 6;

    const int wv = t >> 6, lane = t & 63;
    const int li = lane & 15, lg = lane >> 4, l7 = li & 7;
    const int lb3 = (li >> 3) << 2;

    // ---- persistent staging source pointers (granule j*256 + t) ----
    const float* xslab = x + (((size_t)(b * 64)) * 512 + (size_t)hb * 8) * 512 + wc * 16;
    const float* gp[8];
#pragma unroll
    for (int j = 0; j < 8; ++j) {
        const int G = j * 256 + t;
        const int c = G >> 5;
        const int v = (G & 31) ^ (c & 7);
        const int r = v >> 2, qg = v & 3;
        gp[j] = xslab + (size_t)c * 262144 + r * 512 + qg * 4;
    }
    float* lbase = &xs[wv * 256];     // wave-uniform LDS base; + j*1024 per inst

    // ---- stage T matrices into LDS (once): physical slot (c,s) holds
    // logical granule kg = s ^ (c&15). ----
#pragma unroll
    for (int j = 0; j < 4; ++j) {
        const int g = j * 256 + t;    // physical granule id
        const int c = g >> 4, s = g & 15;
        const int kg = s ^ (c & 15);
        *(f4*)&ts[c * 64 + s * 4] = *(const f4*)(twm + c * 64 + kg * 4);
    }

    // ---- W fragments (fp16) + biases ----
    h8 w1f[2], w2f[2];
    {
        const float* p1 = w1 + (16 * wv + li) * 64 + lg * 8;
        const float* p2 = w2 + (16 * wv + li) * 64 + lg * 8;
#pragma unroll
        for (int kk = 0; kk < 2; ++kk) {
            f4 a = *(const f4*)(p1 + kk * 32);
            f4 d = *(const f4*)(p1 + kk * 32 + 4);
            h8 f;
#pragma unroll
            for (int q = 0; q < 4; ++q) { f[q] = (_Float16)a[q]; f[4 + q] = (_Float16)d[q]; }
            w1f[kk] = f;
            a = *(const f4*)(p2 + kk * 32);
            d = *(const f4*)(p2 + kk * 32 + 4);
#pragma unroll
            for (int q = 0; q < 4; ++q) { f[q] = (_Float16)a[q]; f[4 + q] = (_Float16)d[q]; }
            w2f[kk] = f;
        }
    }
    const int o0 = 16 * wv + 4 * lg;
    const f4 b1v = *(const f4*)(b1 + o0);
    const float b2s = b2[16 * wv + li];
    const int sg0 = ((lg       ^ l7 ^ lb3) << 3);
    const int sg1 = (((4 + lg) ^ l7 ^ lb3) << 3);
    const int go  = o0 >> 3, co = 4 * (lg & 1);
    const int ch  = 16 * wv + li;
    const int cgE = ch >> 3, c7E = li & 7;

    // ---- transform identity (lane pair shares (c,blk); q-partitioned) ----
    const int pid = t >> 1, h2 = t & 1;
    const int c   = pid & 63, blk = pid >> 6, Q0 = 4 * h2;
    const int tc  = c * 64, c15 = c & 15;    // ts base / XOR key
    const int sc = c * 128, swc = c & 7;
    const int cg = c >> 3, c7 = c & 7;

    // ================= prologue: stage tile 0 =================
#pragma unroll
    for (int j = 0; j < 8; ++j) gload_lds16(gp[j], lbase + j * 1024);
    asm volatile("s_waitcnt vmcnt(0)" ::: "memory");
    __syncthreads();

    for (int tile = 0; tile < 16; ++tile) {
        const int wt = 2 * tile + wc;

        // ---- transform: xs -> M -> Y -> ysf (fp16, swizzled); T from LDS ----
        {
            float M[8][4];
            {
                f4 Ph[8];
#pragma unroll
                for (int i = 0; i < 8; ++i)
                    Ph[i] = *(const f4*)&xs[sc + ((i * 4 + blk * 2) ^ swc) * 4];
#pragma unroll
                for (int qq = 0; qq < 4; ++qq) {
                    f4 Th = *(const f4*)&ts[tc + ((2 * (Q0 + qq)) ^ c15) * 4];
#pragma unroll
                    for (int i = 0; i < 8; ++i) {
                        float s = Ph[i][0] * Th[0];
                        s = fmaf(Ph[i][1], Th[1], s);
                        s = fmaf(Ph[i][2], Th[2], s);
                        s = fmaf(Ph[i][3], Th[3], s);
                        M[i][qq] = s;
                    }
                }
#pragma unroll
                for (int i = 0; i < 8; ++i)
                    Ph[i] = *(const f4*)&xs[sc + ((i * 4 + blk * 2 + 1) ^ swc) * 4];
#pragma unroll
                for (int qq = 0; qq < 4; ++qq) {
                    f4 Th = *(const f4*)&ts[tc + ((2 * (Q0 + qq) + 1) ^ c15) * 4];
#pragma unroll
                    for (int i = 0; i < 8; ++i) {
                        float s = M[i][qq];
                        s = fmaf(Ph[i][0], Th[0], s);
                        s = fmaf(Ph[i][1], Th[1], s);
                        s = fmaf(Ph[i][2], Th[2], s);
                        s = fmaf(Ph[i][3], Th[3], s);
                        M[i][qq] = s;
                    }
                }
            }
#pragma unroll
            for (int p = 0; p < 8; ++p) {
                f4 a = *(const f4*)&ts[tc + ((2 * p)     ^ c15) * 4];
                f4 d = *(const f4*)&ts[tc + ((2 * p + 1) ^ c15) * 4];
                const int px0 = p * 16 + blk * 8;
#pragma unroll
                for (int qq = 0; qq < 4; ++qq) {
                    const int q = Q0 + qq;
                    float s = a[0] * M[0][qq];
                    s = fmaf(a[1], M[1][qq], s);
                    s = fmaf(a[2], M[2][qq], s);
                    s = fmaf(a[3], M[3][qq], s);
                    s = fmaf(d[0], M[4][qq], s);
                    s = fmaf(d[1], M[5][qq], s);
                    s = fmaf(d[2], M[6][qq], s);
                    s = fmaf(d[3], M[7][qq], s);
                    const int idx = ((cg ^ q ^ (blk << 2)) << 3) | c7;
                    *(_Float16*)&ysf[px0 + q][idx] = (_Float16)s;
                }
            }
        }
        __syncthreads();   // B1: ysf ready, xs consumed

        // ---- issue next tile's staging (drains until just before B3) ----
        if (tile < 15) {
#pragma unroll
            for (int j = 0; j < 8; ++j)
                gload_lds16(gp[j] + (tile + 1) * 32, lbase + j * 1024);
        }

        // ---- GEMM1: H = relu(W1 * Y + b1) ----
        f32x4 acc[8];
#pragma unroll
        for (int j = 0; j < 8; ++j) acc[j] = (f32x4){0.f, 0.f, 0.f, 0.f};
#pragma unroll
        for (int j = 0; j < 8; ++j) {
            const int row = 16 * j + li;
            h8 bh0 = *(const h8*)&ysf[row][sg0];
            h8 bh1 = *(const h8*)&ysf[row][sg1];
            acc[j] = __builtin_amdgcn_mfma_f32_16x16x32_f16(w1f[0], bh0, acc[j], 0, 0, 0);
            acc[j] = __builtin_amdgcn_mfma_f32_16x16x32_f16(w1f[1], bh1, acc[j], 0, 0, 0);
        }
#pragma unroll
        for (int j = 0; j < 8; ++j) {
            const int px = 16 * j + li;
            const int idx = ((go ^ l7 ^ lb3) << 3) + co;
            union { _Float16 h[2]; unsigned u; } p01, p23;
            p01.h[0] = (_Float16)fmaxf(acc[j][0] + b1v[0], 0.f);
            p01.h[1] = (_Float16)fmaxf(acc[j][1] + b1v[1], 0.f);
            p23.h[0] = (_Float16)fmaxf(acc[j][2] + b1v[2], 0.f);
            p23.h[1] = (_Float16)fmaxf(acc[j][3] + b1v[3], 0.f);
            *(unsigned*)&hsf[px][idx]     = p01.u;
            *(unsigned*)&hsf[px][idx + 2] = p23.u;
        }
        __syncthreads();   // B2: hsf ready

        // ---- GEMM2 swapped (A=H, B=W2): D[px][channel]; epilogue f4 stores ----
#pragma unroll
        for (int j = 0; j < 8; ++j) acc[j] = (f32x4){0.f, 0.f, 0.f, 0.f};
#pragma unroll
        for (int j = 0; j < 8; ++j) {
            const int row = 16 * j + li;
            h8 ah0 = *(const h8*)&hsf[row][sg0];
            h8 ah1 = *(const h8*)&hsf[row][sg1];
            acc[j] = __builtin_amdgcn_mfma_f32_16x16x32_f16(ah0, w2f[0], acc[j], 0, 0, 0);
            acc[j] = __builtin_amdgcn_mfma_f32_16x16x32_f16(ah1, w2f[1], acc[j], 0, 0, 0);
        }
        float* oB = out + ((size_t)(b * 64) + ch) * 262144
                    + (size_t)(hb * 8) * 512 + wt * 16 + 4 * lg;
#pragma unroll
        for (int j = 0; j < 8; ++j) {
            f4 r;
#pragma unroll
            for (int r4 = 0; r4 < 4; ++r4) {
                const int pc = 4 * lg + r4;
                const int px = 16 * j + pc;
                const int idx = ((cgE ^ (pc & 7) ^ (((pc >> 3) & 1) << 2)) << 3) | c7E;
                float yv = (float)(*(const _Float16*)&ysf[px][idx]);
                float z = acc[j][r4] + b2s;
                float g = __builtin_amdgcn_rcpf(1.f + __expf(-z));
                r[r4] = yv * g;
            }
            *(f4*)(oB + (size_t)j * 512) = r;
        }
        // staging must land before next transform reads xs (after B3)
        asm volatile("s_waitcnt vmcnt(0)" ::: "memory");
        __syncthreads();   // B3: ysf/hsf consumed; xs(t+1) resident
    }
}

extern "C" void kernel_launch(void* const* d_in, const int* in_sizes, int n_in,
                              void* d_out, int out_size, void* d_ws, size_t ws_size,
                              hipStream_t stream) {
    (void)in_sizes; (void)n_in; (void)out_size; (void)d_ws; (void)ws_size;
    const float* x   = (const float*)d_in[0];
    const float* twm = (const float*)d_in[1];
    const float* w1  = (const float*)d_in[2];
    const float* b1  = (const float*)d_in[3];
    const float* w2  = (const float*)d_in[4];
    const float* b2  = (const float*)d_in[5];
    float* out = (float*)d_out;

    avif_final<<<dim3(512), dim3(256), 0, stream>>>(x, twm, w1, b1, w2, b2, out);
}